// Round 11
// baseline (236.425 us; speedup 1.0000x reference)
//
#include <hip/hip_runtime.h>

#define DD 64        // embedding dim
#define RPCB 256     // rows per coarse bucket
#define CBSH 8       // log2(RPCB)
#define NBLK_P 512   // partition blocks (p1/p2)

static inline size_t align16(size_t x) { return (x + 15) & ~(size_t)15; }

__device__ __forceinline__ unsigned bf16rn(float f) {
    unsigned u = __float_as_uint(f);
    return (u + 0x7fffu + ((u >> 16) & 1u)) >> 16;   // RNE
}

typedef __attribute__((ext_vector_type(8))) short bf16x8;  // 8 bf16 (4 VGPRs)
typedef __attribute__((ext_vector_type(4))) float f32x4;   // 4 fp32 acc

// ---------------- P1: per-block histogram over coarse buckets ----------------
__global__ __launch_bounds__(1024) void p1_hist(
    const int* __restrict__ srows, const int* __restrict__ irows,
    int* __restrict__ hmat, int ES, int EI, int U, int CB, int EPB)
{
    __shared__ int hist[1024];         // CB <= 1024 (U <= 131072)
    const int b = blockIdx.x, t = threadIdx.x;
    for (int i = t; i < CB; i += 1024) hist[i] = 0;
    __syncthreads();
    const int e0 = b * EPB, e1 = min(e0 + EPB, ES + EI);
    for (int e = e0 + t; e < e1; e += 1024) {
        int row = (e < ES) ? srows[e] : U + irows[e - ES];
        atomicAdd(&hist[row >> CBSH], 1);
    }
    __syncthreads();
    for (int i = t; i < CB; i += 1024) hmat[(size_t)i * NBLK_P + b] = hist[i];
}

// ---------------- scan helpers ----------------
__global__ __launch_bounds__(256) void scan_partial(
    const int* __restrict__ in, int* __restrict__ out, int* __restrict__ bsums, int n)
{
    __shared__ int sh[256];
    int base = blockIdx.x * 2048 + threadIdx.x * 8;
    int v[8];
    int tsum = 0;
    #pragma unroll
    for (int j = 0; j < 8; ++j) {
        int idx = base + j;
        int x = (idx < n) ? in[idx] : 0;
        v[j] = tsum;
        tsum += x;
    }
    sh[threadIdx.x] = tsum;
    __syncthreads();
    for (int off = 1; off < 256; off <<= 1) {
        int t = (threadIdx.x >= off) ? sh[threadIdx.x - off] : 0;
        __syncthreads();
        sh[threadIdx.x] += t;
        __syncthreads();
    }
    int texc = sh[threadIdx.x] - tsum;
    #pragma unroll
    for (int j = 0; j < 8; ++j) {
        int idx = base + j;
        if (idx < n) out[idx] = texc + v[j];
    }
    if (threadIdx.x == 255) bsums[blockIdx.x] = sh[255];
}

__global__ void scan_top(int* bsums, int nb)
{
    int run = 0;
    for (int i = 0; i < nb; ++i) { int t = bsums[i]; bsums[i] = run; run += t; }
}

__global__ __launch_bounds__(256) void scan_add(
    int* __restrict__ out, const int* __restrict__ bsums, int n)
{
    int i = blockIdx.x * 256 + threadIdx.x;
    if (i < n) out[i] += bsums[i >> 11];
}

// ---------------- P2: partition scatter into per-(bucket,block) exclusive ranges ----------------
// payload: .x = (row_lo << 17) | col  (row_lo 8b, col <= 17b), .y = fp32 val bits
__global__ __launch_bounds__(1024) void p2_scatter(
    const int* __restrict__ srows, const int* __restrict__ scols, const float* __restrict__ svals,
    const int* __restrict__ irows, const int* __restrict__ icols, const float* __restrict__ ivals,
    const int* __restrict__ hS, uint2* __restrict__ bedges,
    int ES, int EI, int U, int CB, int EPB)
{
    __shared__ int cur[1024];
    const int b = blockIdx.x, t = threadIdx.x;
    for (int i = t; i < CB; i += 1024) cur[i] = hS[(size_t)i * NBLK_P + b];
    __syncthreads();
    const int e0 = b * EPB, e1 = min(e0 + EPB, ES + EI);
    for (int e = e0 + t; e < e1; e += 1024) {
        int row, col; unsigned val;
        if (e < ES) { row = srows[e]; col = scols[e]; val = __float_as_uint(svals[e]); }
        else {
            int i = e - ES;
            row = U + irows[i]; col = icols[i]; val = __float_as_uint(ivals[i]);
        }
        int slot = atomicAdd(&cur[row >> CBSH], 1);
        bedges[slot] = make_uint2(((unsigned)(row & (RPCB - 1)) << 17) | (unsigned)col, val);
    }
}

// ---------------- P3: per-bucket finalize -> row_ptr + exact CSR slots ----------------
__global__ __launch_bounds__(256) void p3_fin(
    const uint2* __restrict__ bedges, const int* __restrict__ hS,
    int* __restrict__ row_ptr, uint2* __restrict__ edges,
    int n2, int Etot, int CB)
{
    __shared__ int cnt[RPCB];
    __shared__ int sh[256];
    const int cb = blockIdx.x, t = threadIdx.x;
    const int r0 = cb << CBSH;
    const int s = hS[(size_t)cb * NBLK_P];
    const int e = (cb == CB - 1) ? Etot : hS[(size_t)(cb + 1) * NBLK_P];

    cnt[t] = 0;
    __syncthreads();
    for (int i = s + t; i < e; i += 256) atomicAdd(&cnt[bedges[i].x >> 17], 1);
    __syncthreads();

    int c = cnt[t];
    sh[t] = c;
    __syncthreads();
    for (int off = 1; off < 256; off <<= 1) {
        int v = (t >= off) ? sh[t - off] : 0;
        __syncthreads();
        sh[t] += v;
        __syncthreads();
    }
    int excl = sh[t] - c;
    int v = s + excl;
    cnt[t] = v;                         // becomes cursor
    int gr = r0 + t;
    if (gr < n2) row_ptr[gr] = v;
    if (cb == CB - 1 && t == 0) row_ptr[n2] = Etot;
    __syncthreads();

    for (int i = s + t; i < e; i += 256) {
        uint2 ev = bedges[i];
        int r = ev.x >> 17;
        int slot = atomicAdd(&cnt[r], 1);
        edges[slot] = make_uint2(ev.x & 0x1FFFFu, ev.y);
    }
}

// ---------------- fp32 -> bf16 tables; item half also writes fp32 passthrough ----------------
__global__ __launch_bounds__(256) void f32_to_bf16_2(
    const float* __restrict__ inA, ushort* __restrict__ outA, int n8A,
    const float* __restrict__ inB, ushort* __restrict__ outB,
    float* __restrict__ passB, int n8B)
{
    int i = blockIdx.x * 256 + threadIdx.x;
    const float* in; ushort* out; float* pass = nullptr;
    if (i < n8A) { in = inA; out = outA; }
    else if (i < n8A + n8B) { i -= n8A; in = inB; out = outB; pass = passB; }
    else return;
    const float4* p = reinterpret_cast<const float4*>(in) + (size_t)i * 2;
    float4 A = p[0], B = p[1];
    uint4 r;
    r.x = bf16rn(A.x) | (bf16rn(A.y) << 16);
    r.y = bf16rn(A.z) | (bf16rn(A.w) << 16);
    r.z = bf16rn(B.x) | (bf16rn(B.y) << 16);
    r.w = bf16rn(B.z) | (bf16rn(B.w) << 16);
    reinterpret_cast<uint4*>(out)[i] = r;
    if (pass) {
        float4* q = reinterpret_cast<float4*>(pass) + (size_t)i * 2;
        q[0] = A; q[1] = B;
    }
}

// ---------------- weights: fp32 [L][128][64] -> bf16 W^T [L][64][128] ----------------
__global__ __launch_bounds__(256) void conv_w(
    const float* __restrict__ w, ushort* __restrict__ wtb, int n)  // n = L*8192
{
    int idx = blockIdx.x * 256 + threadIdx.x;
    if (idx >= n) return;
    int l = idx >> 13;
    int r = idx & 8191;
    int c = r >> 7;          // col 0..63
    int k = r & 127;         // k   0..127
    wtb[idx] = (ushort)bf16rn(w[(size_t)l * 8192 + k * 64 + c]);
}

// ---------------- helpers: bf16x8 (uint4) FMA into two float4 ----------------
__device__ __forceinline__ void fmadd16(float4& a0, float4& a1, unsigned vb, uint4 x)
{
    float v = __uint_as_float(vb);
    a0.x += v * __uint_as_float(x.x << 16);
    a0.y += v * __uint_as_float(x.x & 0xffff0000u);
    a0.z += v * __uint_as_float(x.y << 16);
    a0.w += v * __uint_as_float(x.y & 0xffff0000u);
    a1.x += v * __uint_as_float(x.z << 16);
    a1.y += v * __uint_as_float(x.z & 0xffff0000u);
    a1.z += v * __uint_as_float(x.w << 16);
    a1.w += v * __uint_as_float(x.w & 0xffff0000u);
}

// ---------------- inter SpMM: write fp32 tmpI (8 lanes/row, 16B gathers) ----------------
__global__ __launch_bounds__(256) void spmm_inter(
    const int* __restrict__ row_ptr, const uint2* __restrict__ edges,
    const ushort* __restrict__ xb,   // bf16 [nx,64]
    float* __restrict__ outf, int nrows)
{
    int g    = (blockIdx.x * 256 + threadIdx.x) >> 3;
    int lane = threadIdx.x & 7;
    if (g >= nrows) return;
    int s = row_ptr[g], e = row_ptr[g + 1];
    float4 a0 = make_float4(0.f, 0.f, 0.f, 0.f);
    float4 a1 = make_float4(0.f, 0.f, 0.f, 0.f);
    int i = s;
    for (; i + 3 < e; i += 4) {
        uint2 e0 = edges[i], e1 = edges[i + 1], e2 = edges[i + 2], e3 = edges[i + 3];
        uint4 x0 = *reinterpret_cast<const uint4*>(xb + ((size_t)e0.x << 6) + lane * 8);
        uint4 x1 = *reinterpret_cast<const uint4*>(xb + ((size_t)e1.x << 6) + lane * 8);
        uint4 x2 = *reinterpret_cast<const uint4*>(xb + ((size_t)e2.x << 6) + lane * 8);
        uint4 x3 = *reinterpret_cast<const uint4*>(xb + ((size_t)e3.x << 6) + lane * 8);
        fmadd16(a0, a1, e0.y, x0);
        fmadd16(a0, a1, e1.y, x1);
        fmadd16(a0, a1, e2.y, x2);
        fmadd16(a0, a1, e3.y, x3);
    }
    for (; i < e; ++i) {
        uint2 e0 = edges[i];
        uint4 x0 = *reinterpret_cast<const uint4*>(xb + ((size_t)e0.x << 6) + lane * 8);
        fmadd16(a0, a1, e0.y, x0);
    }
    float* o = outf + ((size_t)g << 6) + lane * 8;
    *reinterpret_cast<float4*>(o)     = a0;
    *reinterpret_cast<float4*>(o + 4) = a1;
}

// ---------------- fused layer: social spmm (-> LDS bf16) + MFMA concat-GEMM ----------------
// Block = 256 threads, 64 dest rows. Phase 1: 4 lanes/row gather (each lane 16 cols, 2x16B),
// register-accumulate, one swizzled LDS store. Phase 2: MFMA; A first half from LDS
// (granule-swizzle g^(row&7), 2-way conflicts = free), second half (uprev) from global.
// C/D mapping: col=lane&15, row=(lane>>4)*4+reg [HW-verified].
template<bool FINAL>
__global__ __launch_bounds__(256) void fused_layer(
    const int* __restrict__ row_ptr,
    const uint2* __restrict__ edges,
    const ushort* __restrict__ uprev,  // bf16 [U,64] gather table + concat-b half
    const ushort* __restrict__ wtb,    // bf16 W^T [64,128] for this layer
    const float* __restrict__ tmpI,    // FINAL: fp32 [U,64] inter spmm result
    float* __restrict__ outf,          // FINAL: fp32 [U,64]
    ushort* __restrict__ outb,         // !FINAL: bf16 [U,64]
    int U)
{
    __shared__ ushort sWt[64 * 128];   // 16 KB, [col][k] granule-swizzled g^(c&7)
    __shared__ ushort sIn[64 * 64];    // 8 KB, [row][64] granule-swizzled g^(row&7)
    const int t = threadIdx.x;

    // stage W^T
    for (int i = t; i < 1024; i += 256) {
        int c = i >> 4, g = i & 15;
        uint4 v = *reinterpret_cast<const uint4*>(wtb + (size_t)c * 128 + g * 8);
        int gp = g ^ (c & 7);
        *reinterpret_cast<uint4*>(&sWt[c * 128 + gp * 8]) = v;
    }

    // phase 1: social gather for this block's 64 rows
    {
        const int lrow = t >> 2;          // 0..63
        const int lane = t & 3;           // owns cols lane*16 .. +15
        const int grow = blockIdx.x * 64 + lrow;
        if (grow < U) {
            int s = row_ptr[grow], e = row_ptr[grow + 1];
            float4 a0 = make_float4(0.f,0.f,0.f,0.f), a1 = a0, a2 = a0, a3 = a0;
            int i = s;
            for (; i + 1 < e; i += 2) {
                uint2 e0 = edges[i], e1 = edges[i + 1];
                const ushort* r0 = uprev + ((size_t)e0.x << 6) + lane * 16;
                const ushort* r1 = uprev + ((size_t)e1.x << 6) + lane * 16;
                uint4 x00 = *reinterpret_cast<const uint4*>(r0);
                uint4 x01 = *reinterpret_cast<const uint4*>(r0 + 8);
                uint4 x10 = *reinterpret_cast<const uint4*>(r1);
                uint4 x11 = *reinterpret_cast<const uint4*>(r1 + 8);
                fmadd16(a0, a1, e0.y, x00);
                fmadd16(a2, a3, e0.y, x01);
                fmadd16(a0, a1, e1.y, x10);
                fmadd16(a2, a3, e1.y, x11);
            }
            if (i < e) {
                uint2 e0 = edges[i];
                const ushort* r0 = uprev + ((size_t)e0.x << 6) + lane * 16;
                uint4 x00 = *reinterpret_cast<const uint4*>(r0);
                uint4 x01 = *reinterpret_cast<const uint4*>(r0 + 8);
                fmadd16(a0, a1, e0.y, x00);
                fmadd16(a2, a3, e0.y, x01);
            }
            uint4 pk0, pk1;
            pk0.x = bf16rn(a0.x) | (bf16rn(a0.y) << 16);
            pk0.y = bf16rn(a0.z) | (bf16rn(a0.w) << 16);
            pk0.z = bf16rn(a1.x) | (bf16rn(a1.y) << 16);
            pk0.w = bf16rn(a1.z) | (bf16rn(a1.w) << 16);
            pk1.x = bf16rn(a2.x) | (bf16rn(a2.y) << 16);
            pk1.y = bf16rn(a2.z) | (bf16rn(a2.w) << 16);
            pk1.z = bf16rn(a3.x) | (bf16rn(a3.y) << 16);
            pk1.w = bf16rn(a3.z) | (bf16rn(a3.w) << 16);
            int g0 = 2 * lane, g1 = 2 * lane + 1;
            *reinterpret_cast<uint4*>(&sIn[lrow * 64 + (g0 ^ (lrow & 7)) * 8]) = pk0;
            *reinterpret_cast<uint4*>(&sIn[lrow * 64 + (g1 ^ (lrow & 7)) * 8]) = pk1;
        }
    }
    __syncthreads();

    // phase 2: MFMA concat-GEMM
    const int w    = t >> 6;
    const int l    = t & 63;
    const int l16  = l & 15;
    const int ksub = l >> 4;
    const int grow_base = blockIdx.x * 64 + w * 16;
    const int arow = min(grow_base + l16, U - 1);
    const int rloc = w * 16 + l16;

    f32x4 acc[4] = {f32x4{0,0,0,0}, f32x4{0,0,0,0}, f32x4{0,0,0,0}, f32x4{0,0,0,0}};

    #pragma unroll
    for (int kk = 0; kk < 4; ++kk) {
        bf16x8 afrag;
        if (kk < 2) {
            int ga = kk * 4 + ksub;       // 0..7
            afrag = *reinterpret_cast<const bf16x8*>(&sIn[rloc * 64 + (ga ^ (rloc & 7)) * 8]);
        } else {
            int kof = kk * 32 + ksub * 8 - 64;
            afrag = *reinterpret_cast<const bf16x8*>(uprev + ((size_t)arow << 6) + kof);
        }
        #pragma unroll
        for (int ct = 0; ct < 4; ++ct) {
            int c  = ct * 16 + l16;
            int g  = kk * 4 + ksub;
            int gp = g ^ (c & 7);
            bf16x8 bfrag = *reinterpret_cast<const bf16x8*>(&sWt[c * 128 + gp * 8]);
            acc[ct] = __builtin_amdgcn_mfma_f32_16x16x32_bf16(afrag, bfrag, acc[ct], 0, 0, 0);
        }
    }

    #pragma unroll
    for (int ct = 0; ct < 4; ++ct) {
        #pragma unroll
        for (int j = 0; j < 4; ++j) {
            int grow = grow_base + ksub * 4 + j;
            int gcol = ct * 16 + l16;
            if (grow < U) {
                float v = acc[ct][j];
                if (FINAL) {
                    outf[((size_t)grow << 6) + gcol] = v + tmpI[((size_t)grow << 6) + gcol];
                } else {
                    outb[((size_t)grow << 6) + gcol] = (ushort)bf16rn(v);
                }
            }
        }
    }
}

extern "C" void kernel_launch(void* const* d_in, const int* in_sizes, int n_in,
                              void* d_out, int out_size, void* d_ws, size_t ws_size,
                              hipStream_t stream)
{
    const float* user_emb    = (const float*)d_in[0];
    const float* item_emb    = (const float*)d_in[1];
    const float* weights     = (const float*)d_in[2];
    const float* social_vals = (const float*)d_in[3];
    const float* inter_vals  = (const float*)d_in[4];
    const int*   social_rows = (const int*)d_in[5];
    const int*   social_cols = (const int*)d_in[6];
    const int*   inter_rows  = (const int*)d_in[7];
    const int*   inter_cols  = (const int*)d_in[8];

    const int D  = DD;
    const int U  = in_sizes[0] / D;
    const int I  = in_sizes[1] / D;
    const int L  = in_sizes[2] / (2 * D * D);
    const int ES = in_sizes[3];
    const int EI = in_sizes[4];

    float* out      = (float*)d_out;           // final_u [U, D]
    float* out_item = out + (size_t)U * D;     // item_emb passthrough [I, D]

    // ---- workspace layout ----
    char* p = (char*)d_ws;
    size_t off = 0;
    auto take = [&](size_t bytes) { char* r = p + off; off += align16(bytes); return r; };

    const int n2   = 2 * U;
    const int CB   = (n2 + RPCB - 1) >> CBSH;       // coarse buckets (<= 1024)
    const int Etot = ES + EI;
    const int EPB  = (Etot + NBLK_P - 1) / NBLK_P;  // edges per partition block
    const int NH   = CB * NBLK_P;

    int*    row_ptr = (int*)take((size_t)(n2 + 1) * sizeof(int));
    int*    hmat    = (int*)take((size_t)NH * sizeof(int));
    int*    hS      = (int*)take((size_t)NH * sizeof(int));
    int*    bsums   = (int*)take(1024 * sizeof(int));
    uint2*  edges   = (uint2*)take((size_t)Etot * sizeof(uint2));
    uint2*  bedges  = (uint2*)take((size_t)Etot * sizeof(uint2));
    ushort* ubf     = (ushort*)take((size_t)U * D * sizeof(ushort));
    ushort* ibf     = (ushort*)take((size_t)I * D * sizeof(ushort));
    ushort* wtb     = (ushort*)take((size_t)L * 2 * D * D * sizeof(ushort));
    float*  tmpI    = (float*)take((size_t)U * D * sizeof(float));
    ushort* uB_bf   = (ushort*)take((size_t)U * D * sizeof(ushort));
    ushort* uC_bf   = (ushort*)take((size_t)U * D * sizeof(ushort));

    // ---- CSR build: partition histogram -> scan -> partition scatter -> bucket finalize ----
    p1_hist<<<NBLK_P, 1024, 0, stream>>>(social_rows, inter_rows, hmat, ES, EI, U, CB, EPB);
    const int nb = (NH + 2047) / 2048;
    scan_partial<<<nb, 256, 0, stream>>>(hmat, hS, bsums, NH);
    scan_top<<<1, 1, 0, stream>>>(bsums, nb);
    scan_add<<<(NH + 255) / 256, 256, 0, stream>>>(hS, bsums, NH);
    p2_scatter<<<NBLK_P, 1024, 0, stream>>>(
        social_rows, social_cols, social_vals,
        inter_rows, inter_cols, inter_vals,
        hS, bedges, ES, EI, U, CB, EPB);
    p3_fin<<<CB, 256, 0, stream>>>(bedges, hS, row_ptr, edges, n2, Etot, CB);

    // ---- bf16 conversions (item half also emits the fp32 passthrough output) ----
    const int u8 = U * D / 8, i8 = I * D / 8;
    f32_to_bf16_2<<<(u8 + i8 + 255) / 256, 256, 0, stream>>>(
        user_emb, ubf, u8, item_emb, ibf, out_item, i8);
    const int nw = L * 2 * D * D;
    conv_w<<<(nw + 255) / 256, 256, 0, stream>>>(weights, wtb, nw);

    // ---- inter spmm early (independent of layers): tmpI = A_inter @ item ----
    const int ispmm_grid = ((U * 8) + 255) / 256;
    spmm_inter<<<ispmm_grid, 256, 0, stream>>>(row_ptr + U, edges, ibf, tmpI, U);

    // ---- fused layers ----
    const int fl_grid = (U + 63) / 64;
    const ushort* uprev = ubf;
    int which = 0;
    for (int k = 0; k < L; ++k) {
        const ushort* wk = wtb + (size_t)k * 2 * D * D;
        if (k == L - 1) {
            fused_layer<true><<<fl_grid, 256, 0, stream>>>(
                row_ptr, edges, uprev, wk, tmpI, out, (ushort*)nullptr, U);
        } else {
            ushort* unext = which ? uC_bf : uB_bf;
            fused_layer<false><<<fl_grid, 256, 0, stream>>>(
                row_ptr, edges, uprev, wk, (const float*)nullptr,
                (float*)nullptr, unext, U);
            uprev = unext;
            which ^= 1;
        }
    }
}

// Round 13
// 213.819 us; speedup vs baseline: 1.1057x; 1.1057x over previous
//
#include <hip/hip_runtime.h>

#define DD 64        // embedding dim
#define RPCB 256     // rows per coarse bucket
#define CBSH 8       // log2(RPCB)
#define NBLK_P 512   // partition blocks (p1/p2)

static inline size_t align16(size_t x) { return (x + 15) & ~(size_t)15; }

__device__ __forceinline__ unsigned bf16rn(float f) {
    unsigned u = __float_as_uint(f);
    return (u + 0x7fffu + ((u >> 16) & 1u)) >> 16;   // RNE
}

typedef __attribute__((ext_vector_type(8))) short bf16x8;  // 8 bf16 (4 VGPRs)
typedef __attribute__((ext_vector_type(4))) float f32x4;   // 4 fp32 acc

#define VAL_SCALE 32767.0f
#define VAL_INV   (1.0f / 32767.0f)

// ---------------- P1: per-block histogram over coarse buckets ----------------
__global__ __launch_bounds__(1024) void p1_hist(
    const int* __restrict__ srows, const int* __restrict__ irows,
    int* __restrict__ hmat, int ES, int EI, int U, int CB, int EPB)
{
    __shared__ int hist[1024];         // CB <= 1024 (U <= 131072)
    const int b = blockIdx.x, t = threadIdx.x;
    for (int i = t; i < CB; i += 1024) hist[i] = 0;
    __syncthreads();
    const int e0 = b * EPB, e1 = min(e0 + EPB, ES + EI);
    for (int e = e0 + t; e < e1; e += 1024) {
        int row = (e < ES) ? srows[e] : U + irows[e - ES];
        atomicAdd(&hist[row >> CBSH], 1);
    }
    __syncthreads();
    for (int i = t; i < CB; i += 1024) hmat[(size_t)i * NBLK_P + b] = hist[i];
}

// ---------------- scan helpers ----------------
__global__ __launch_bounds__(256) void scan_partial(
    const int* __restrict__ in, int* __restrict__ out, int* __restrict__ bsums, int n)
{
    __shared__ int sh[256];
    int base = blockIdx.x * 2048 + threadIdx.x * 8;
    int v[8];
    int tsum = 0;
    #pragma unroll
    for (int j = 0; j < 8; ++j) {
        int idx = base + j;
        int x = (idx < n) ? in[idx] : 0;
        v[j] = tsum;
        tsum += x;
    }
    sh[threadIdx.x] = tsum;
    __syncthreads();
    for (int off = 1; off < 256; off <<= 1) {
        int t = (threadIdx.x >= off) ? sh[threadIdx.x - off] : 0;
        __syncthreads();
        sh[threadIdx.x] += t;
        __syncthreads();
    }
    int texc = sh[threadIdx.x] - tsum;
    #pragma unroll
    for (int j = 0; j < 8; ++j) {
        int idx = base + j;
        if (idx < n) out[idx] = texc + v[j];
    }
    if (threadIdx.x == 255) bsums[blockIdx.x] = sh[255];
}

__global__ void scan_top(int* bsums, int nb)
{
    int run = 0;
    for (int i = 0; i < nb; ++i) { int t = bsums[i]; bsums[i] = run; run += t; }
}

__global__ __launch_bounds__(256) void scan_add(
    int* __restrict__ out, const int* __restrict__ bsums, int n)
{
    int i = blockIdx.x * 256 + threadIdx.x;
    if (i < n) out[i] += bsums[i >> 11];
}

// ---------------- P2: partition scatter into per-(bucket,block) exclusive ranges ----------------
// bpacked: col | (q15 << 17); brow: bucket-local row byte
__global__ __launch_bounds__(1024) void p2_scatter(
    const int* __restrict__ srows, const int* __restrict__ scols, const float* __restrict__ svals,
    const int* __restrict__ irows, const int* __restrict__ icols, const float* __restrict__ ivals,
    const int* __restrict__ hS, unsigned* __restrict__ bpacked, unsigned char* __restrict__ brow,
    int ES, int EI, int U, int CB, int EPB)
{
    __shared__ int cur[1024];
    const int b = blockIdx.x, t = threadIdx.x;
    for (int i = t; i < CB; i += 1024) cur[i] = hS[(size_t)i * NBLK_P + b];
    __syncthreads();
    const int e0 = b * EPB, e1 = min(e0 + EPB, ES + EI);
    for (int e = e0 + t; e < e1; e += 1024) {
        int row, col; float val;
        if (e < ES) { row = srows[e]; col = scols[e]; val = svals[e]; }
        else {
            int i = e - ES;
            row = U + irows[i]; col = icols[i]; val = ivals[i];
        }
        unsigned q = (unsigned)(val * VAL_SCALE + 0.5f);   // val in [0,1)
        int slot = atomicAdd(&cur[row >> CBSH], 1);
        bpacked[slot] = (unsigned)col | (q << 17);
        brow[slot]    = (unsigned char)(row & (RPCB - 1));
    }
}

// ---------------- P3: per-bucket finalize -> row_ptr + exact CSR slots ----------------
__global__ __launch_bounds__(256) void p3_fin(
    const unsigned* __restrict__ bpacked, const unsigned char* __restrict__ brow,
    const int* __restrict__ hS,
    int* __restrict__ row_ptr, unsigned* __restrict__ edges,
    int n2, int Etot, int CB)
{
    __shared__ int cnt[RPCB];
    __shared__ int sh[256];
    const int cb = blockIdx.x, t = threadIdx.x;
    const int r0 = cb << CBSH;
    const int s = hS[(size_t)cb * NBLK_P];
    const int e = (cb == CB - 1) ? Etot : hS[(size_t)(cb + 1) * NBLK_P];

    cnt[t] = 0;
    __syncthreads();
    for (int i = s + t; i < e; i += 256) atomicAdd(&cnt[brow[i]], 1);
    __syncthreads();

    int c = cnt[t];
    sh[t] = c;
    __syncthreads();
    for (int off = 1; off < 256; off <<= 1) {
        int v = (t >= off) ? sh[t - off] : 0;
        __syncthreads();
        sh[t] += v;
        __syncthreads();
    }
    int excl = sh[t] - c;
    int v = s + excl;
    cnt[t] = v;                         // becomes cursor
    int gr = r0 + t;
    if (gr < n2) row_ptr[gr] = v;
    if (cb == CB - 1 && t == 0) row_ptr[n2] = Etot;
    __syncthreads();

    for (int i = s + t; i < e; i += 256) {
        int r = brow[i];
        int slot = atomicAdd(&cnt[r], 1);
        edges[slot] = bpacked[i];
    }
}

// ---------------- conv: user fp32 -> bf16 + int8(rowscale); item fp32 -> int8 + passthrough ----------------
// 8 lanes per row (32B fp32 per lane). Biased-ubyte storage: b = round(x/s)+128, s = rowmax/127.
__global__ __launch_bounds__(256) void conv_quant(
    const float* __restrict__ uemb, ushort* __restrict__ ubf,
    unsigned char* __restrict__ uq8, float* __restrict__ uscale, int U,
    const float* __restrict__ iemb, unsigned char* __restrict__ iq8,
    float* __restrict__ iscale, float* __restrict__ passI, int I)
{
    int row  = (blockIdx.x * 256 + threadIdx.x) >> 3;
    int lane = threadIdx.x & 7;
    bool isU = (row < U);
    int lrow = isU ? row : row - U;
    if (!isU && lrow >= I) return;
    const float* src = (isU ? uemb : iemb) + ((size_t)lrow << 6) + lane * 8;
    float4 A = *reinterpret_cast<const float4*>(src);
    float4 B = *reinterpret_cast<const float4*>(src + 4);
    float m = fmaxf(fmaxf(fmaxf(fabsf(A.x), fabsf(A.y)), fmaxf(fabsf(A.z), fabsf(A.w))),
                    fmaxf(fmaxf(fabsf(B.x), fabsf(B.y)), fmaxf(fabsf(B.z), fabsf(B.w))));
    m = fmaxf(m, __shfl_xor(m, 1, 8));
    m = fmaxf(m, __shfl_xor(m, 2, 8));
    m = fmaxf(m, __shfl_xor(m, 4, 8));
    float inv = (m > 1e-30f) ? 127.0f / m : 0.0f;
    float sc  = m / 127.0f;
    unsigned b0 = (unsigned)(__float2int_rn(A.x * inv) + 128);
    unsigned b1 = (unsigned)(__float2int_rn(A.y * inv) + 128);
    unsigned b2 = (unsigned)(__float2int_rn(A.z * inv) + 128);
    unsigned b3 = (unsigned)(__float2int_rn(A.w * inv) + 128);
    unsigned b4 = (unsigned)(__float2int_rn(B.x * inv) + 128);
    unsigned b5 = (unsigned)(__float2int_rn(B.y * inv) + 128);
    unsigned b6 = (unsigned)(__float2int_rn(B.z * inv) + 128);
    unsigned b7 = (unsigned)(__float2int_rn(B.w * inv) + 128);
    uint2 pk = make_uint2(b0 | (b1 << 8) | (b2 << 16) | (b3 << 24),
                          b4 | (b5 << 8) | (b6 << 16) | (b7 << 24));
    if (isU) {
        reinterpret_cast<uint2*>(uq8 + ((size_t)lrow << 6) + lane * 8)[0] = pk;
        if (lane == 0) uscale[lrow] = sc;
        uint4 r;
        r.x = bf16rn(A.x) | (bf16rn(A.y) << 16);
        r.y = bf16rn(A.z) | (bf16rn(A.w) << 16);
        r.z = bf16rn(B.x) | (bf16rn(B.y) << 16);
        r.w = bf16rn(B.z) | (bf16rn(B.w) << 16);
        *reinterpret_cast<uint4*>(ubf + ((size_t)lrow << 6) + lane * 8) = r;
    } else {
        reinterpret_cast<uint2*>(iq8 + ((size_t)lrow << 6) + lane * 8)[0] = pk;
        if (lane == 0) iscale[lrow] = sc;
        float* q = passI + ((size_t)lrow << 6) + lane * 8;
        *reinterpret_cast<float4*>(q)     = A;
        *reinterpret_cast<float4*>(q + 4) = B;
    }
}

// ---------------- rows_to_i8: bf16 [n,64] -> int8 + rowscale ----------------
__global__ __launch_bounds__(256) void rows_to_i8(
    const ushort* __restrict__ bf, unsigned char* __restrict__ q8,
    float* __restrict__ scale, int nrows)
{
    int row  = (blockIdx.x * 256 + threadIdx.x) >> 3;
    int lane = threadIdx.x & 7;
    if (row >= nrows) return;
    uint4 x = *reinterpret_cast<const uint4*>(bf + ((size_t)row << 6) + lane * 8);
    float v0 = __uint_as_float(x.x << 16), v1 = __uint_as_float(x.x & 0xffff0000u);
    float v2 = __uint_as_float(x.y << 16), v3 = __uint_as_float(x.y & 0xffff0000u);
    float v4 = __uint_as_float(x.z << 16), v5 = __uint_as_float(x.z & 0xffff0000u);
    float v6 = __uint_as_float(x.w << 16), v7 = __uint_as_float(x.w & 0xffff0000u);
    float m = fmaxf(fmaxf(fmaxf(fabsf(v0), fabsf(v1)), fmaxf(fabsf(v2), fabsf(v3))),
                    fmaxf(fmaxf(fabsf(v4), fabsf(v5)), fmaxf(fabsf(v6), fabsf(v7))));
    m = fmaxf(m, __shfl_xor(m, 1, 8));
    m = fmaxf(m, __shfl_xor(m, 2, 8));
    m = fmaxf(m, __shfl_xor(m, 4, 8));
    float inv = (m > 1e-30f) ? 127.0f / m : 0.0f;
    unsigned b0 = (unsigned)(__float2int_rn(v0 * inv) + 128);
    unsigned b1 = (unsigned)(__float2int_rn(v1 * inv) + 128);
    unsigned b2 = (unsigned)(__float2int_rn(v2 * inv) + 128);
    unsigned b3 = (unsigned)(__float2int_rn(v3 * inv) + 128);
    unsigned b4 = (unsigned)(__float2int_rn(v4 * inv) + 128);
    unsigned b5 = (unsigned)(__float2int_rn(v5 * inv) + 128);
    unsigned b6 = (unsigned)(__float2int_rn(v6 * inv) + 128);
    unsigned b7 = (unsigned)(__float2int_rn(v7 * inv) + 128);
    uint2 pk = make_uint2(b0 | (b1 << 8) | (b2 << 16) | (b3 << 24),
                          b4 | (b5 << 8) | (b6 << 16) | (b7 << 24));
    reinterpret_cast<uint2*>(q8 + ((size_t)row << 6) + lane * 8)[0] = pk;
    if (lane == 0) scale[row] = m / 127.0f;
}

// ---------------- weights: fp32 [L][128][64] -> bf16 W^T [L][64][128] ----------------
__global__ __launch_bounds__(256) void conv_w(
    const float* __restrict__ w, ushort* __restrict__ wtb, int n)  // n = L*8192
{
    int idx = blockIdx.x * 256 + threadIdx.x;
    if (idx >= n) return;
    int l = idx >> 13;
    int r = idx & 8191;
    int c = r >> 7;          // col 0..63
    int k = r & 127;         // k   0..127
    wtb[idx] = (ushort)bf16rn(w[(size_t)l * 8192 + k * 64 + c]);
}

// ---------------- SpMM (CSR row-gather, int8 rowscale source, fp32 accumulate) ----------------
// 8 lanes/row, 8 B int8 gather per lane. x = scale_c*(b-128); contribution folded via ssum.
__device__ __forceinline__ void fma_i8(float4& a0, float4& a1, float& ssum, float veff, uint2 x)
{
    ssum += veff;
    a0.x += veff * (float)(x.x & 0xffu);
    a0.y += veff * (float)((x.x >> 8) & 0xffu);
    a0.z += veff * (float)((x.x >> 16) & 0xffu);
    a0.w += veff * (float)(x.x >> 24);
    a1.x += veff * (float)(x.y & 0xffu);
    a1.y += veff * (float)((x.y >> 8) & 0xffu);
    a1.z += veff * (float)((x.y >> 16) & 0xffu);
    a1.w += veff * (float)(x.y >> 24);
}

// MODE 0: write bf16; MODE 1: add into fp32 out
template <int MODE>
__global__ __launch_bounds__(256) void spmm_i8(
    const int* __restrict__ row_ptr, const unsigned* __restrict__ edges,
    const unsigned char* __restrict__ q8,   // int8 [nx,64] biased
    const float* __restrict__ scalef,       // [nx]
    ushort* __restrict__ outb, float* __restrict__ outf, int nrows)
{
    int g    = (blockIdx.x * 256 + threadIdx.x) >> 3;
    int lane = threadIdx.x & 7;
    if (g >= nrows) return;
    int s = row_ptr[g], e = row_ptr[g + 1];
    float4 a0 = make_float4(0.f, 0.f, 0.f, 0.f);
    float4 a1 = make_float4(0.f, 0.f, 0.f, 0.f);
    float ssum = 0.f;
    int i = s;
    for (; i + 3 < e; i += 4) {
        unsigned e0 = edges[i], e1 = edges[i + 1], e2 = edges[i + 2], e3 = edges[i + 3];
        unsigned c0 = e0 & 0x1FFFFu, c1 = e1 & 0x1FFFFu, c2 = e2 & 0x1FFFFu, c3 = e3 & 0x1FFFFu;
        uint2 x0 = *reinterpret_cast<const uint2*>(q8 + ((size_t)c0 << 6) + lane * 8);
        uint2 x1 = *reinterpret_cast<const uint2*>(q8 + ((size_t)c1 << 6) + lane * 8);
        uint2 x2 = *reinterpret_cast<const uint2*>(q8 + ((size_t)c2 << 6) + lane * 8);
        uint2 x3 = *reinterpret_cast<const uint2*>(q8 + ((size_t)c3 << 6) + lane * 8);
        float v0 = (float)(e0 >> 17) * VAL_INV * scalef[c0];
        float v1 = (float)(e1 >> 17) * VAL_INV * scalef[c1];
        float v2 = (float)(e2 >> 17) * VAL_INV * scalef[c2];
        float v3 = (float)(e3 >> 17) * VAL_INV * scalef[c3];
        fma_i8(a0, a1, ssum, v0, x0);
        fma_i8(a0, a1, ssum, v1, x1);
        fma_i8(a0, a1, ssum, v2, x2);
        fma_i8(a0, a1, ssum, v3, x3);
    }
    for (; i < e; ++i) {
        unsigned e0 = edges[i];
        unsigned c0 = e0 & 0x1FFFFu;
        uint2 x0 = *reinterpret_cast<const uint2*>(q8 + ((size_t)c0 << 6) + lane * 8);
        float v0 = (float)(e0 >> 17) * VAL_INV * scalef[c0];
        fma_i8(a0, a1, ssum, v0, x0);
    }
    float bias = 128.f * ssum;
    a0.x -= bias; a0.y -= bias; a0.z -= bias; a0.w -= bias;
    a1.x -= bias; a1.y -= bias; a1.z -= bias; a1.w -= bias;
    if (MODE == 0) {
        uint4 pk;
        pk.x = bf16rn(a0.x) | (bf16rn(a0.y) << 16);
        pk.y = bf16rn(a0.z) | (bf16rn(a0.w) << 16);
        pk.z = bf16rn(a1.x) | (bf16rn(a1.y) << 16);
        pk.w = bf16rn(a1.z) | (bf16rn(a1.w) << 16);
        *reinterpret_cast<uint4*>(outb + ((size_t)g << 6) + lane * 8) = pk;
    } else {
        float* o = outf + ((size_t)g << 6) + lane * 8;
        float4 c0 = *reinterpret_cast<const float4*>(o);
        float4 c1 = *reinterpret_cast<const float4*>(o + 4);
        a0.x += c0.x; a0.y += c0.y; a0.z += c0.z; a0.w += c0.w;
        a1.x += c1.x; a1.y += c1.y; a1.z += c1.z; a1.w += c1.w;
        *reinterpret_cast<float4*>(o)     = a0;
        *reinterpret_cast<float4*>(o + 4) = a1;
    }
}

// ---------------- MFMA concat-GEMM: out[r,:] = [a[r,:], b[r,:]] @ W ----------------
// Block = 256 threads = 4 waves; 64 rows/block. A-frags from global; W^T bf16 in LDS,
// granule-swizzled. C/D mapping: col=lane&15, row=(lane>>4)*4+reg [HW-verified].
template<bool FINAL>
__global__ __launch_bounds__(256) void gemm_mfma(
    const ushort* __restrict__ abf,   // bf16 [U,64] spmm result
    const ushort* __restrict__ bbf,   // bf16 [U,64] prev u
    const ushort* __restrict__ wtb,   // bf16 W^T [64,128] for this layer
    float* __restrict__ outf,         // FINAL: fp32 [U,64]
    ushort* __restrict__ outb,        // !FINAL: bf16 [U,64]
    int U)
{
    __shared__ ushort sWt[64 * 128];  // 16 KB, [col][k], granule-swizzled
    const int t = threadIdx.x;

    for (int i = t; i < 1024; i += 256) {
        int c = i >> 4, g = i & 15;
        uint4 v = *reinterpret_cast<const uint4*>(wtb + (size_t)c * 128 + g * 8);
        int gp = g ^ (c & 7);
        *reinterpret_cast<uint4*>(&sWt[c * 128 + gp * 8]) = v;
    }
    __syncthreads();

    const int w    = t >> 6;
    const int l    = t & 63;
    const int l16  = l & 15;
    const int ksub = l >> 4;
    const int grow_base = blockIdx.x * 64 + w * 16;

    const int arow = min(grow_base + l16, U - 1);

    f32x4 acc[4] = {f32x4{0,0,0,0}, f32x4{0,0,0,0}, f32x4{0,0,0,0}, f32x4{0,0,0,0}};

    #pragma unroll
    for (int kk = 0; kk < 4; ++kk) {
        const int kof = kk * 32 + ksub * 8;
        const ushort* asrc = (kk < 2) ? (abf + ((size_t)arow << 6) + kof)
                                      : (bbf + ((size_t)arow << 6) + (kof - 64));
        bf16x8 afrag = *reinterpret_cast<const bf16x8*>(asrc);
        #pragma unroll
        for (int ct = 0; ct < 4; ++ct) {
            int c  = ct * 16 + l16;
            int g  = kk * 4 + ksub;
            int gp = g ^ (c & 7);
            bf16x8 bfrag = *reinterpret_cast<const bf16x8*>(&sWt[c * 128 + gp * 8]);
            acc[ct] = __builtin_amdgcn_mfma_f32_16x16x32_bf16(afrag, bfrag, acc[ct], 0, 0, 0);
        }
    }

    #pragma unroll
    for (int ct = 0; ct < 4; ++ct) {
        #pragma unroll
        for (int j = 0; j < 4; ++j) {
            int grow = grow_base + ksub * 4 + j;
            int gcol = ct * 16 + l16;
            if (grow < U) {
                float v = acc[ct][j];
                if (FINAL) outf[((size_t)grow << 6) + gcol] = v;
                else       outb[((size_t)grow << 6) + gcol] = (ushort)bf16rn(v);
            }
        }
    }
}

extern "C" void kernel_launch(void* const* d_in, const int* in_sizes, int n_in,
                              void* d_out, int out_size, void* d_ws, size_t ws_size,
                              hipStream_t stream)
{
    const float* user_emb    = (const float*)d_in[0];
    const float* item_emb    = (const float*)d_in[1];
    const float* weights     = (const float*)d_in[2];
    const float* social_vals = (const float*)d_in[3];
    const float* inter_vals  = (const float*)d_in[4];
    const int*   social_rows = (const int*)d_in[5];
    const int*   social_cols = (const int*)d_in[6];
    const int*   inter_rows  = (const int*)d_in[7];
    const int*   inter_cols  = (const int*)d_in[8];

    const int D  = DD;
    const int U  = in_sizes[0] / D;
    const int I  = in_sizes[1] / D;
    const int L  = in_sizes[2] / (2 * D * D);
    const int ES = in_sizes[3];
    const int EI = in_sizes[4];

    float* out      = (float*)d_out;           // final_u [U, D]
    float* out_item = out + (size_t)U * D;     // item_emb passthrough [I, D]

    // ---- workspace layout ----
    char* p = (char*)d_ws;
    size_t off = 0;
    auto take = [&](size_t bytes) { char* r = p + off; off += align16(bytes); return r; };

    const int n2   = 2 * U;
    const int CB   = (n2 + RPCB - 1) >> CBSH;       // coarse buckets (<= 1024)
    const int Etot = ES + EI;
    const int EPB  = (Etot + NBLK_P - 1) / NBLK_P;  // edges per partition block
    const int NH   = CB * NBLK_P;

    int*           row_ptr = (int*)take((size_t)(n2 + 1) * sizeof(int));
    int*           hmat    = (int*)take((size_t)NH * sizeof(int));
    int*           hS      = (int*)take((size_t)NH * sizeof(int));
    int*           bsums   = (int*)take(1024 * sizeof(int));
    unsigned*      edges   = (unsigned*)take((size_t)Etot * sizeof(unsigned));
    unsigned*      bpacked = (unsigned*)take((size_t)Etot * sizeof(unsigned));
    unsigned char* brow    = (unsigned char*)take((size_t)Etot);
    ushort*        ubf     = (ushort*)take((size_t)U * D * sizeof(ushort));
    unsigned char* uq8     = (unsigned char*)take((size_t)U * D);
    float*         uscale  = (float*)take((size_t)U * sizeof(float));
    unsigned char* iq8     = (unsigned char*)take((size_t)I * D);
    float*         iscale  = (float*)take((size_t)I * sizeof(float));
    ushort*        wtb     = (ushort*)take((size_t)L * 2 * D * D * sizeof(ushort));
    ushort*        tmpA_bf = (ushort*)take((size_t)U * D * sizeof(ushort));
    ushort*        uB_bf   = (ushort*)take((size_t)U * D * sizeof(ushort));
    ushort*        uC_bf   = (ushort*)take((size_t)U * D * sizeof(ushort));
    unsigned char* uB_q8   = (unsigned char*)take((size_t)U * D);
    unsigned char* uC_q8   = (unsigned char*)take((size_t)U * D);
    float*         uB_sc   = (float*)take((size_t)U * sizeof(float));
    float*         uC_sc   = (float*)take((size_t)U * sizeof(float));

    // ---- CSR build: partition histogram -> scan -> partition scatter -> bucket finalize ----
    p1_hist<<<NBLK_P, 1024, 0, stream>>>(social_rows, inter_rows, hmat, ES, EI, U, CB, EPB);
    const int nb = (NH + 2047) / 2048;
    scan_partial<<<nb, 256, 0, stream>>>(hmat, hS, bsums, NH);
    scan_top<<<1, 1, 0, stream>>>(bsums, nb);
    scan_add<<<(NH + 255) / 256, 256, 0, stream>>>(hS, bsums, NH);
    p2_scatter<<<NBLK_P, 1024, 0, stream>>>(
        social_rows, social_cols, social_vals,
        inter_rows, inter_cols, inter_vals,
        hS, bpacked, brow, ES, EI, U, CB, EPB);
    p3_fin<<<CB, 256, 0, stream>>>(bpacked, brow, hS, row_ptr, edges, n2, Etot, CB);

    // ---- tables: user bf16+int8, item int8 + fp32 passthrough ----
    const int convthreads = (U + I) * 8;
    conv_quant<<<(convthreads + 255) / 256, 256, 0, stream>>>(
        user_emb, ubf, uq8, uscale, U, item_emb, iq8, iscale, out_item, I);
    const int nw = L * 2 * D * D;
    conv_w<<<(nw + 255) / 256, 256, 0, stream>>>(weights, wtb, nw);

    // ---- layers ----
    const int spmm_grid = ((U * 8) + 255) / 256;
    const int gemm_grid = (U + 63) / 64;
    const ushort*        uprev_bf = ubf;
    const unsigned char* uprev_q8 = uq8;
    const float*         uprev_sc = uscale;
    int which = 0;
    for (int k = 0; k < L; ++k) {
        const ushort* wk = wtb + (size_t)k * 2 * D * D;
        spmm_i8<0><<<spmm_grid, 256, 0, stream>>>(
            row_ptr, edges, uprev_q8, uprev_sc, tmpA_bf, (float*)nullptr, U);
        if (k == L - 1) {
            gemm_mfma<true><<<gemm_grid, 256, 0, stream>>>(
                tmpA_bf, uprev_bf, wk, out, (ushort*)nullptr, U);
        } else {
            ushort*        nbf = which ? uC_bf : uB_bf;
            unsigned char* nq8 = which ? uC_q8 : uB_q8;
            float*         nsc = which ? uC_sc : uB_sc;
            gemm_mfma<false><<<gemm_grid, 256, 0, stream>>>(
                tmpA_bf, uprev_bf, wk, (float*)nullptr, nbf, U);
            rows_to_i8<<<spmm_grid, 256, 0, stream>>>(nbf, nq8, nsc, U);
            uprev_bf = nbf;
            uprev_q8 = nq8;
            uprev_sc = nsc;
            which ^= 1;
        }
    }

    // final_u += A_inter @ item_emb (int8 gather, fp32 accumulate into d_out)
    spmm_i8<1><<<spmm_grid, 256, 0, stream>>>(
        row_ptr + U, edges, iq8, iscale, (ushort*)nullptr, out, U);
}

// Round 14
// 186.735 us; speedup vs baseline: 1.2661x; 1.1450x over previous
//
#include <hip/hip_runtime.h>

#define DD 64        // embedding dim
#define RPCB 1024    // rows per coarse bucket
#define CBSH 10      // log2(RPCB)
#define NBLK_P 256   // partition blocks (p1/p2), 1024 threads each

static inline size_t align16(size_t x) { return (x + 15) & ~(size_t)15; }

__device__ __forceinline__ unsigned bf16rn(float f) {
    unsigned u = __float_as_uint(f);
    return (u + 0x7fffu + ((u >> 16) & 1u)) >> 16;   // RNE
}

typedef __attribute__((ext_vector_type(8))) short bf16x8;  // 8 bf16 (4 VGPRs)
typedef __attribute__((ext_vector_type(4))) float f32x4;   // 4 fp32 acc

#define VAL_SCALE 32767.0f
#define VAL_INV   (1.0f / 32767.0f)

// ---------------- P1: per-block histogram over coarse buckets ----------------
__global__ __launch_bounds__(1024) void p1_hist(
    const int* __restrict__ srows, const int* __restrict__ irows,
    int* __restrict__ hmat, int ES, int EI, int U, int CB, int EPB)
{
    __shared__ int hist[256];          // CB <= 256 (U <= 131072)
    const int b = blockIdx.x, t = threadIdx.x;
    for (int i = t; i < CB; i += 1024) hist[i] = 0;
    __syncthreads();
    const int e0 = b * EPB, e1 = min(e0 + EPB, ES + EI);
    for (int e = e0 + t; e < e1; e += 1024) {
        int row = (e < ES) ? srows[e] : U + irows[e - ES];
        atomicAdd(&hist[row >> CBSH], 1);
    }
    __syncthreads();
    for (int i = t; i < CB; i += 1024) hmat[(size_t)i * NBLK_P + b] = hist[i];
}

// ---------------- scan helpers ----------------
__global__ __launch_bounds__(256) void scan_partial(
    const int* __restrict__ in, int* __restrict__ out, int* __restrict__ bsums, int n)
{
    __shared__ int sh[256];
    int base = blockIdx.x * 2048 + threadIdx.x * 8;
    int v[8];
    int tsum = 0;
    #pragma unroll
    for (int j = 0; j < 8; ++j) {
        int idx = base + j;
        int x = (idx < n) ? in[idx] : 0;
        v[j] = tsum;
        tsum += x;
    }
    sh[threadIdx.x] = tsum;
    __syncthreads();
    for (int off = 1; off < 256; off <<= 1) {
        int t = (threadIdx.x >= off) ? sh[threadIdx.x - off] : 0;
        __syncthreads();
        sh[threadIdx.x] += t;
        __syncthreads();
    }
    int texc = sh[threadIdx.x] - tsum;
    #pragma unroll
    for (int j = 0; j < 8; ++j) {
        int idx = base + j;
        if (idx < n) out[idx] = texc + v[j];
    }
    if (threadIdx.x == 255) bsums[blockIdx.x] = sh[255];
}

__global__ void scan_top(int* bsums, int nb)
{
    int run = 0;
    for (int i = 0; i < nb; ++i) { int t = bsums[i]; bsums[i] = run; run += t; }
}

__global__ __launch_bounds__(256) void scan_add(
    int* __restrict__ out, const int* __restrict__ bsums, int n)
{
    int i = blockIdx.x * 256 + threadIdx.x;
    if (i < n) out[i] += bsums[i >> 11];
}

// ---------------- P2: partition scatter into per-(bucket,block) exclusive ranges ----------------
// bedges: .x = row_lo<<17 | col (sort key), .y = col | q15<<17 (final edge word)
__global__ __launch_bounds__(1024) void p2_scatter(
    const int* __restrict__ srows, const int* __restrict__ scols, const float* __restrict__ svals,
    const int* __restrict__ irows, const int* __restrict__ icols, const float* __restrict__ ivals,
    const int* __restrict__ hS, uint2* __restrict__ bedges,
    int ES, int EI, int U, int CB, int EPB)
{
    __shared__ int cur[256];
    const int b = blockIdx.x, t = threadIdx.x;
    for (int i = t; i < CB; i += 1024) cur[i] = hS[(size_t)i * NBLK_P + b];
    __syncthreads();
    const int e0 = b * EPB, e1 = min(e0 + EPB, ES + EI);
    for (int e = e0 + t; e < e1; e += 1024) {
        int row, col; float val;
        if (e < ES) { row = srows[e]; col = scols[e]; val = svals[e]; }
        else {
            int i = e - ES;
            row = U + irows[i]; col = icols[i]; val = ivals[i];
        }
        unsigned q = (unsigned)(val * VAL_SCALE + 0.5f);   // val in [0,1)
        int slot = atomicAdd(&cur[row >> CBSH], 1);
        bedges[slot] = make_uint2(((unsigned)(row & (RPCB - 1)) << 17) | (unsigned)col,
                                  (unsigned)col | (q << 17));
    }
}

// ---------------- P3: per-bucket finalize -> row_ptr + exact CSR slots ----------------
__global__ __launch_bounds__(256) void p3_fin(
    const uint2* __restrict__ bedges, const int* __restrict__ hS,
    int* __restrict__ row_ptr, unsigned* __restrict__ edges,
    int n2, int Etot, int CB)
{
    __shared__ int cnt[RPCB];
    __shared__ int sh[256];
    const int cb = blockIdx.x, t = threadIdx.x;
    const int r0 = cb << CBSH;
    const int s = hS[(size_t)cb * NBLK_P];
    const int e = (cb == CB - 1) ? Etot : hS[(size_t)(cb + 1) * NBLK_P];

    #pragma unroll
    for (int j = 0; j < RPCB / 256; ++j) cnt[t + j * 256] = 0;
    __syncthreads();
    for (int i = s + t; i < e; i += 256) atomicAdd(&cnt[bedges[i].x >> 17], 1);
    __syncthreads();

    // exclusive scan of cnt[RPCB]: 4 consecutive per thread + block scan
    int c[4]; int tot = 0;
    #pragma unroll
    for (int j = 0; j < 4; ++j) { int x = cnt[t * 4 + j]; c[j] = tot; tot += x; }
    sh[t] = tot;
    __syncthreads();
    for (int off = 1; off < 256; off <<= 1) {
        int v = (t >= off) ? sh[t - off] : 0;
        __syncthreads();
        sh[t] += v;
        __syncthreads();
    }
    int excl = sh[t] - tot;
    #pragma unroll
    for (int j = 0; j < 4; ++j) {
        int r = t * 4 + j;
        int v = s + excl + c[j];
        cnt[r] = v;                         // becomes cursor
        int gr = r0 + r;
        if (gr < n2) row_ptr[gr] = v;
    }
    if (cb == CB - 1 && t == 0) row_ptr[n2] = Etot;
    __syncthreads();

    for (int i = s + t; i < e; i += 256) {
        uint2 ev = bedges[i];
        int r = ev.x >> 17;
        int slot = atomicAdd(&cnt[r], 1);
        edges[slot] = ev.y;
    }
}

// ---------------- conv: user fp32 -> bf16 + int8(rowscale); item fp32 -> int8 + passthrough ----------------
// 8 lanes per row. Biased-ubyte storage: b = round(x/s)+128, s = rowmax/127.
__global__ __launch_bounds__(256) void conv_quant(
    const float* __restrict__ uemb, ushort* __restrict__ ubf,
    unsigned char* __restrict__ uq8, float* __restrict__ uscale, int U,
    const float* __restrict__ iemb, unsigned char* __restrict__ iq8,
    float* __restrict__ iscale, float* __restrict__ passI, int I)
{
    int row  = (blockIdx.x * 256 + threadIdx.x) >> 3;
    int lane = threadIdx.x & 7;
    bool isU = (row < U);
    int lrow = isU ? row : row - U;
    if (!isU && lrow >= I) return;
    const float* src = (isU ? uemb : iemb) + ((size_t)lrow << 6) + lane * 8;
    float4 A = *reinterpret_cast<const float4*>(src);
    float4 B = *reinterpret_cast<const float4*>(src + 4);
    float m = fmaxf(fmaxf(fmaxf(fabsf(A.x), fabsf(A.y)), fmaxf(fabsf(A.z), fabsf(A.w))),
                    fmaxf(fmaxf(fabsf(B.x), fabsf(B.y)), fmaxf(fabsf(B.z), fabsf(B.w))));
    m = fmaxf(m, __shfl_xor(m, 1, 8));
    m = fmaxf(m, __shfl_xor(m, 2, 8));
    m = fmaxf(m, __shfl_xor(m, 4, 8));
    float inv = (m > 1e-30f) ? 127.0f / m : 0.0f;
    float sc  = m / 127.0f;
    unsigned b0 = (unsigned)(__float2int_rn(A.x * inv) + 128);
    unsigned b1 = (unsigned)(__float2int_rn(A.y * inv) + 128);
    unsigned b2 = (unsigned)(__float2int_rn(A.z * inv) + 128);
    unsigned b3 = (unsigned)(__float2int_rn(A.w * inv) + 128);
    unsigned b4 = (unsigned)(__float2int_rn(B.x * inv) + 128);
    unsigned b5 = (unsigned)(__float2int_rn(B.y * inv) + 128);
    unsigned b6 = (unsigned)(__float2int_rn(B.z * inv) + 128);
    unsigned b7 = (unsigned)(__float2int_rn(B.w * inv) + 128);
    uint2 pk = make_uint2(b0 | (b1 << 8) | (b2 << 16) | (b3 << 24),
                          b4 | (b5 << 8) | (b6 << 16) | (b7 << 24));
    if (isU) {
        reinterpret_cast<uint2*>(uq8 + ((size_t)lrow << 6) + lane * 8)[0] = pk;
        if (lane == 0) uscale[lrow] = sc;
        uint4 r;
        r.x = bf16rn(A.x) | (bf16rn(A.y) << 16);
        r.y = bf16rn(A.z) | (bf16rn(A.w) << 16);
        r.z = bf16rn(B.x) | (bf16rn(B.y) << 16);
        r.w = bf16rn(B.z) | (bf16rn(B.w) << 16);
        *reinterpret_cast<uint4*>(ubf + ((size_t)lrow << 6) + lane * 8) = r;
    } else {
        reinterpret_cast<uint2*>(iq8 + ((size_t)lrow << 6) + lane * 8)[0] = pk;
        if (lane == 0) iscale[lrow] = sc;
        float* q = passI + ((size_t)lrow << 6) + lane * 8;
        *reinterpret_cast<float4*>(q)     = A;
        *reinterpret_cast<float4*>(q + 4) = B;
    }
}

// ---------------- rows_to_i8: bf16 [n,64] -> int8 + rowscale ----------------
__global__ __launch_bounds__(256) void rows_to_i8(
    const ushort* __restrict__ bf, unsigned char* __restrict__ q8,
    float* __restrict__ scale, int nrows)
{
    int row  = (blockIdx.x * 256 + threadIdx.x) >> 3;
    int lane = threadIdx.x & 7;
    if (row >= nrows) return;
    uint4 x = *reinterpret_cast<const uint4*>(bf + ((size_t)row << 6) + lane * 8);
    float v0 = __uint_as_float(x.x << 16), v1 = __uint_as_float(x.x & 0xffff0000u);
    float v2 = __uint_as_float(x.y << 16), v3 = __uint_as_float(x.y & 0xffff0000u);
    float v4 = __uint_as_float(x.z << 16), v5 = __uint_as_float(x.z & 0xffff0000u);
    float v6 = __uint_as_float(x.w << 16), v7 = __uint_as_float(x.w & 0xffff0000u);
    float m = fmaxf(fmaxf(fmaxf(fabsf(v0), fabsf(v1)), fmaxf(fabsf(v2), fabsf(v3))),
                    fmaxf(fmaxf(fabsf(v4), fabsf(v5)), fmaxf(fabsf(v6), fabsf(v7))));
    m = fmaxf(m, __shfl_xor(m, 1, 8));
    m = fmaxf(m, __shfl_xor(m, 2, 8));
    m = fmaxf(m, __shfl_xor(m, 4, 8));
    float inv = (m > 1e-30f) ? 127.0f / m : 0.0f;
    unsigned b0 = (unsigned)(__float2int_rn(v0 * inv) + 128);
    unsigned b1 = (unsigned)(__float2int_rn(v1 * inv) + 128);
    unsigned b2 = (unsigned)(__float2int_rn(v2 * inv) + 128);
    unsigned b3 = (unsigned)(__float2int_rn(v3 * inv) + 128);
    unsigned b4 = (unsigned)(__float2int_rn(v4 * inv) + 128);
    unsigned b5 = (unsigned)(__float2int_rn(v5 * inv) + 128);
    unsigned b6 = (unsigned)(__float2int_rn(v6 * inv) + 128);
    unsigned b7 = (unsigned)(__float2int_rn(v7 * inv) + 128);
    uint2 pk = make_uint2(b0 | (b1 << 8) | (b2 << 16) | (b3 << 24),
                          b4 | (b5 << 8) | (b6 << 16) | (b7 << 24));
    reinterpret_cast<uint2*>(q8 + ((size_t)row << 6) + lane * 8)[0] = pk;
    if (lane == 0) scale[row] = m / 127.0f;
}

// ---------------- weights: fp32 [L][128][64] -> bf16 W^T [L][64][128] ----------------
__global__ __launch_bounds__(256) void conv_w(
    const float* __restrict__ w, ushort* __restrict__ wtb, int n)  // n = L*8192
{
    int idx = blockIdx.x * 256 + threadIdx.x;
    if (idx >= n) return;
    int l = idx >> 13;
    int r = idx & 8191;
    int c = r >> 7;          // col 0..63
    int k = r & 127;         // k   0..127
    wtb[idx] = (ushort)bf16rn(w[(size_t)l * 8192 + k * 64 + c]);
}

// ---------------- SpMM (CSR row-gather, int8 rowscale source, fp32 accumulate) ----------------
__device__ __forceinline__ void fma_i8(float4& a0, float4& a1, float& ssum, float veff, uint2 x)
{
    ssum += veff;
    a0.x += veff * (float)(x.x & 0xffu);
    a0.y += veff * (float)((x.x >> 8) & 0xffu);
    a0.z += veff * (float)((x.x >> 16) & 0xffu);
    a0.w += veff * (float)(x.x >> 24);
    a1.x += veff * (float)(x.y & 0xffu);
    a1.y += veff * (float)((x.y >> 8) & 0xffu);
    a1.z += veff * (float)((x.y >> 16) & 0xffu);
    a1.w += veff * (float)(x.y >> 24);
}

// MODE 0: write bf16; MODE 1: add into fp32 out
template <int MODE>
__global__ __launch_bounds__(256) void spmm_i8(
    const int* __restrict__ row_ptr, const unsigned* __restrict__ edges,
    const unsigned char* __restrict__ q8,   // int8 [nx,64] biased
    const float* __restrict__ scalef,       // [nx]
    ushort* __restrict__ outb, float* __restrict__ outf, int nrows)
{
    int g    = (blockIdx.x * 256 + threadIdx.x) >> 3;
    int lane = threadIdx.x & 7;
    if (g >= nrows) return;
    int s = row_ptr[g], e = row_ptr[g + 1];
    float4 a0 = make_float4(0.f, 0.f, 0.f, 0.f);
    float4 a1 = make_float4(0.f, 0.f, 0.f, 0.f);
    float ssum = 0.f;
    int i = s;
    for (; i + 3 < e; i += 4) {
        unsigned e0 = edges[i], e1 = edges[i + 1], e2 = edges[i + 2], e3 = edges[i + 3];
        unsigned c0 = e0 & 0x1FFFFu, c1 = e1 & 0x1FFFFu, c2 = e2 & 0x1FFFFu, c3 = e3 & 0x1FFFFu;
        uint2 x0 = *reinterpret_cast<const uint2*>(q8 + ((size_t)c0 << 6) + lane * 8);
        uint2 x1 = *reinterpret_cast<const uint2*>(q8 + ((size_t)c1 << 6) + lane * 8);
        uint2 x2 = *reinterpret_cast<const uint2*>(q8 + ((size_t)c2 << 6) + lane * 8);
        uint2 x3 = *reinterpret_cast<const uint2*>(q8 + ((size_t)c3 << 6) + lane * 8);
        float v0 = (float)(e0 >> 17) * VAL_INV * scalef[c0];
        float v1 = (float)(e1 >> 17) * VAL_INV * scalef[c1];
        float v2 = (float)(e2 >> 17) * VAL_INV * scalef[c2];
        float v3 = (float)(e3 >> 17) * VAL_INV * scalef[c3];
        fma_i8(a0, a1, ssum, v0, x0);
        fma_i8(a0, a1, ssum, v1, x1);
        fma_i8(a0, a1, ssum, v2, x2);
        fma_i8(a0, a1, ssum, v3, x3);
    }
    for (; i < e; ++i) {
        unsigned e0 = edges[i];
        unsigned c0 = e0 & 0x1FFFFu;
        uint2 x0 = *reinterpret_cast<const uint2*>(q8 + ((size_t)c0 << 6) + lane * 8);
        float v0 = (float)(e0 >> 17) * VAL_INV * scalef[c0];
        fma_i8(a0, a1, ssum, v0, x0);
    }
    float bias = 128.f * ssum;
    a0.x -= bias; a0.y -= bias; a0.z -= bias; a0.w -= bias;
    a1.x -= bias; a1.y -= bias; a1.z -= bias; a1.w -= bias;
    if (MODE == 0) {
        uint4 pk;
        pk.x = bf16rn(a0.x) | (bf16rn(a0.y) << 16);
        pk.y = bf16rn(a0.z) | (bf16rn(a0.w) << 16);
        pk.z = bf16rn(a1.x) | (bf16rn(a1.y) << 16);
        pk.w = bf16rn(a1.z) | (bf16rn(a1.w) << 16);
        *reinterpret_cast<uint4*>(outb + ((size_t)g << 6) + lane * 8) = pk;
    } else {
        float* o = outf + ((size_t)g << 6) + lane * 8;
        float4 c0 = *reinterpret_cast<const float4*>(o);
        float4 c1 = *reinterpret_cast<const float4*>(o + 4);
        a0.x += c0.x; a0.y += c0.y; a0.z += c0.z; a0.w += c0.w;
        a1.x += c1.x; a1.y += c1.y; a1.z += c1.z; a1.w += c1.w;
        *reinterpret_cast<float4*>(o)     = a0;
        *reinterpret_cast<float4*>(o + 4) = a1;
    }
}

// ---------------- MFMA concat-GEMM: out[r,:] = [a[r,:], b[r,:]] @ W ----------------
template<bool FINAL>
__global__ __launch_bounds__(256) void gemm_mfma(
    const ushort* __restrict__ abf,   // bf16 [U,64] spmm result
    const ushort* __restrict__ bbf,   // bf16 [U,64] prev u
    const ushort* __restrict__ wtb,   // bf16 W^T [64,128] for this layer
    float* __restrict__ outf,         // FINAL: fp32 [U,64]
    ushort* __restrict__ outb,        // !FINAL: bf16 [U,64]
    int U)
{
    __shared__ ushort sWt[64 * 128];  // 16 KB, [col][k], granule-swizzled
    const int t = threadIdx.x;

    for (int i = t; i < 1024; i += 256) {
        int c = i >> 4, g = i & 15;
        uint4 v = *reinterpret_cast<const uint4*>(wtb + (size_t)c * 128 + g * 8);
        int gp = g ^ (c & 7);
        *reinterpret_cast<uint4*>(&sWt[c * 128 + gp * 8]) = v;
    }
    __syncthreads();

    const int w    = t >> 6;
    const int l    = t & 63;
    const int l16  = l & 15;
    const int ksub = l >> 4;
    const int grow_base = blockIdx.x * 64 + w * 16;

    const int arow = min(grow_base + l16, U - 1);

    f32x4 acc[4] = {f32x4{0,0,0,0}, f32x4{0,0,0,0}, f32x4{0,0,0,0}, f32x4{0,0,0,0}};

    #pragma unroll
    for (int kk = 0; kk < 4; ++kk) {
        const int kof = kk * 32 + ksub * 8;
        const ushort* asrc = (kk < 2) ? (abf + ((size_t)arow << 6) + kof)
                                      : (bbf + ((size_t)arow << 6) + (kof - 64));
        bf16x8 afrag = *reinterpret_cast<const bf16x8*>(asrc);
        #pragma unroll
        for (int ct = 0; ct < 4; ++ct) {
            int c  = ct * 16 + l16;
            int g  = kk * 4 + ksub;
            int gp = g ^ (c & 7);
            bf16x8 bfrag = *reinterpret_cast<const bf16x8*>(&sWt[c * 128 + gp * 8]);
            acc[ct] = __builtin_amdgcn_mfma_f32_16x16x32_bf16(afrag, bfrag, acc[ct], 0, 0, 0);
        }
    }

    #pragma unroll
    for (int ct = 0; ct < 4; ++ct) {
        #pragma unroll
        for (int j = 0; j < 4; ++j) {
            int grow = grow_base + ksub * 4 + j;
            int gcol = ct * 16 + l16;
            if (grow < U) {
                float v = acc[ct][j];
                if (FINAL) outf[((size_t)grow << 6) + gcol] = v;
                else       outb[((size_t)grow << 6) + gcol] = (ushort)bf16rn(v);
            }
        }
    }
}

extern "C" void kernel_launch(void* const* d_in, const int* in_sizes, int n_in,
                              void* d_out, int out_size, void* d_ws, size_t ws_size,
                              hipStream_t stream)
{
    const float* user_emb    = (const float*)d_in[0];
    const float* item_emb    = (const float*)d_in[1];
    const float* weights     = (const float*)d_in[2];
    const float* social_vals = (const float*)d_in[3];
    const float* inter_vals  = (const float*)d_in[4];
    const int*   social_rows = (const int*)d_in[5];
    const int*   social_cols = (const int*)d_in[6];
    const int*   inter_rows  = (const int*)d_in[7];
    const int*   inter_cols  = (const int*)d_in[8];

    const int D  = DD;
    const int U  = in_sizes[0] / D;
    const int I  = in_sizes[1] / D;
    const int L  = in_sizes[2] / (2 * D * D);
    const int ES = in_sizes[3];
    const int EI = in_sizes[4];

    float* out      = (float*)d_out;           // final_u [U, D]
    float* out_item = out + (size_t)U * D;     // item_emb passthrough [I, D]

    // ---- workspace layout ----
    char* p = (char*)d_ws;
    size_t off = 0;
    auto take = [&](size_t bytes) { char* r = p + off; off += align16(bytes); return r; };

    const int n2   = 2 * U;
    const int CB   = (n2 + RPCB - 1) >> CBSH;       // coarse buckets (<= 256)
    const int Etot = ES + EI;
    const int EPB  = (Etot + NBLK_P - 1) / NBLK_P;  // edges per partition block
    const int NH   = CB * NBLK_P;

    int*           row_ptr = (int*)take((size_t)(n2 + 1) * sizeof(int));
    int*           hmat    = (int*)take((size_t)NH * sizeof(int));
    int*           hS      = (int*)take((size_t)NH * sizeof(int));
    int*           bsums   = (int*)take(1024 * sizeof(int));
    unsigned*      edges   = (unsigned*)take((size_t)Etot * sizeof(unsigned));
    uint2*         bedges  = (uint2*)take((size_t)Etot * sizeof(uint2));
    ushort*        ubf     = (ushort*)take((size_t)U * D * sizeof(ushort));
    unsigned char* uq8     = (unsigned char*)take((size_t)U * D);
    float*         uscale  = (float*)take((size_t)U * sizeof(float));
    unsigned char* iq8     = (unsigned char*)take((size_t)I * D);
    float*         iscale  = (float*)take((size_t)I * sizeof(float));
    ushort*        wtb     = (ushort*)take((size_t)L * 2 * D * D * sizeof(ushort));
    ushort*        tmpA_bf = (ushort*)take((size_t)U * D * sizeof(ushort));
    ushort*        uB_bf   = (ushort*)take((size_t)U * D * sizeof(ushort));
    ushort*        uC_bf   = (ushort*)take((size_t)U * D * sizeof(ushort));
    unsigned char* uB_q8   = (unsigned char*)take((size_t)U * D);
    unsigned char* uC_q8   = (unsigned char*)take((size_t)U * D);
    float*         uB_sc   = (float*)take((size_t)U * sizeof(float));
    float*         uC_sc   = (float*)take((size_t)U * sizeof(float));

    // ---- CSR build: partition histogram -> scan -> partition scatter -> bucket finalize ----
    p1_hist<<<NBLK_P, 1024, 0, stream>>>(social_rows, inter_rows, hmat, ES, EI, U, CB, EPB);
    const int nb = (NH + 2047) / 2048;
    scan_partial<<<nb, 256, 0, stream>>>(hmat, hS, bsums, NH);
    scan_top<<<1, 1, 0, stream>>>(bsums, nb);
    scan_add<<<(NH + 255) / 256, 256, 0, stream>>>(hS, bsums, NH);
    p2_scatter<<<NBLK_P, 1024, 0, stream>>>(
        social_rows, social_cols, social_vals,
        inter_rows, inter_cols, inter_vals,
        hS, bedges, ES, EI, U, CB, EPB);
    p3_fin<<<CB, 256, 0, stream>>>(bedges, hS, row_ptr, edges, n2, Etot, CB);

    // ---- tables: user bf16+int8, item int8 + fp32 passthrough ----
    const int convthreads = (U + I) * 8;
    conv_quant<<<(convthreads + 255) / 256, 256, 0, stream>>>(
        user_emb, ubf, uq8, uscale, U, item_emb, iq8, iscale, out_item, I);
    const int nw = L * 2 * D * D;
    conv_w<<<(nw + 255) / 256, 256, 0, stream>>>(weights, wtb, nw);

    // ---- layers ----
    const int spmm_grid = ((U * 8) + 255) / 256;
    const int gemm_grid = (U + 63) / 64;
    const ushort*        uprev_bf = ubf;
    const unsigned char* uprev_q8 = uq8;
    const float*         uprev_sc = uscale;
    int which = 0;
    for (int k = 0; k < L; ++k) {
        const ushort* wk = wtb + (size_t)k * 2 * D * D;
        spmm_i8<0><<<spmm_grid, 256, 0, stream>>>(
            row_ptr, edges, uprev_q8, uprev_sc, tmpA_bf, (float*)nullptr, U);
        if (k == L - 1) {
            gemm_mfma<true><<<gemm_grid, 256, 0, stream>>>(
                tmpA_bf, uprev_bf, wk, out, (ushort*)nullptr, U);
        } else {
            ushort*        nbf = which ? uC_bf : uB_bf;
            unsigned char* nq8 = which ? uC_q8 : uB_q8;
            float*         nsc = which ? uC_sc : uB_sc;
            gemm_mfma<false><<<gemm_grid, 256, 0, stream>>>(
                tmpA_bf, uprev_bf, wk, (float*)nullptr, nbf, U);
            rows_to_i8<<<spmm_grid, 256, 0, stream>>>(nbf, nq8, nsc, U);
            uprev_bf = nbf;
            uprev_q8 = nq8;
            uprev_sc = nsc;
            which ^= 1;
        }
    }

    // final_u += A_inter @ item_emb (int8 gather, fp32 accumulate into d_out)
    spmm_i8<1><<<spmm_grid, 256, 0, stream>>>(
        row_ptr + U, edges, iq8, iscale, (ushort*)nullptr, out, U);
}